// Round 4
// baseline (242.073 us; speedup 1.0000x reference)
//
#include <hip/hip_runtime.h>

#define N_DIM 8192   // rows of features / columns of w / output length
#define K_DIM 512    // inner dim of features @ E
#define D_DIM 4096   // columns of E / rows of w

typedef __bf16 bf16x8 __attribute__((ext_vector_type(8)));
typedef float  f32x16 __attribute__((ext_vector_type(16)));
typedef unsigned short u16x8 __attribute__((ext_vector_type(8)));

__device__ __forceinline__ unsigned short f2bf(float f) {
    union { float f; unsigned int u; } v; v.f = f;
    unsigned int r = v.u + 0x7FFF + ((v.u >> 16) & 1);   // RNE
    return (unsigned short)(r >> 16);
}

// ---------------------------------------------------------------------------
// Kernel 1: E [512][4096] f32  ->  ET [4096][512] bf16 (k-contiguous rows)
// ---------------------------------------------------------------------------
__global__ __launch_bounds__(256) void transpose_E(const float* __restrict__ E,
                                                   unsigned short* __restrict__ ET) {
    __shared__ float tile[64][65];
    const int d0 = blockIdx.x * 64;
    const int k0 = blockIdx.y * 64;
    const int tid = threadIdx.x;
    const int r  = tid / 16;          // 0..15
    const int c4 = (tid % 16) * 4;    // 0..60
#pragma unroll
    for (int p = 0; p < 4; ++p) {
        int k = p * 16 + r;
        float4 v = *reinterpret_cast<const float4*>(E + (size_t)(k0 + k) * D_DIM + d0 + c4);
        tile[k][c4 + 0] = v.x; tile[k][c4 + 1] = v.y;
        tile[k][c4 + 2] = v.z; tile[k][c4 + 3] = v.w;
    }
    __syncthreads();
#pragma unroll
    for (int p = 0; p < 4; ++p) {
        int d = p * 16 + r;
        ushort4 o;
        o.x = f2bf(tile[c4 + 0][d]);
        o.y = f2bf(tile[c4 + 1][d]);
        o.z = f2bf(tile[c4 + 2][d]);
        o.w = f2bf(tile[c4 + 3][d]);
        *reinterpret_cast<ushort4*>(ET + (size_t)(d0 + d) * K_DIM + k0 + c4) = o;
    }
}

// ---------------------------------------------------------------------------
// Kernel 2: F [8192][512] f32 -> FB bf16 (k-contiguous rows).
// Blocks 0..7 also zero the 8192-float output.
// ---------------------------------------------------------------------------
__global__ __launch_bounds__(256) void convert_F(const float* __restrict__ F,
                                                 unsigned short* __restrict__ FB,
                                                 float* __restrict__ out) {
    if (blockIdx.x < 8) {
        float4 z = {0.f, 0.f, 0.f, 0.f};
        *reinterpret_cast<float4*>(out + (blockIdx.x * 256 + threadIdx.x) * 4) = z;
    }
    const int idx8 = (blockIdx.x * 256 + threadIdx.x) * 8;
    float4 a = *reinterpret_cast<const float4*>(F + idx8);
    float4 b = *reinterpret_cast<const float4*>(F + idx8 + 4);
    u16x8 o;
    o[0] = f2bf(a.x); o[1] = f2bf(a.y); o[2] = f2bf(a.z); o[3] = f2bf(a.w);
    o[4] = f2bf(b.x); o[5] = f2bf(b.y); o[6] = f2bf(b.z); o[7] = f2bf(b.w);
    *reinterpret_cast<u16x8*>(FB + idx8) = o;
}

// ---------------------------------------------------------------------------
// Kernel 3: fused  out[n] = sum_d (F@E + b)[n,d] * w[d,n], computed as y^T:
// C-tile 128(d) x 128(n), BK=64, 4 waves (2x2), 32x32x16 bf16 MFMA.
//
// Round 4: the K-loop structure was the cost, not W (4 neutral W experiments).
// Old loop: single-buffered LDS, 2 barriers/kt, stage-drain fully exposed.
// New loop: DOUBLE-BUFFERED LDS (64 KB, still 2 blocks/CU), ONE raw barrier
// per kt, counted-vmcnt discipline: issue kt+1's staging into buf^1 FIRST,
// compute on buf under it (stage L2 latency hides beneath 16 ds_read+16 MFMA),
// then vmcnt(0)+s_barrier. Barrier count halves; stage stall leaves the
// critical path. W back to plain NT epilogue stream (proven non-lever).
// ---------------------------------------------------------------------------
__global__ __launch_bounds__(256, 2) void gemm_fused(const unsigned short* __restrict__ FB,
                                                     const float* __restrict__ W,
                                                     const unsigned short* __restrict__ ET,
                                                     const float* __restrict__ B,
                                                     float* __restrict__ out) {
    // [buf][p-half][row][chunk] ; buf stride 8192 shorts, p stride 4096
    __shared__ unsigned short Ash[2 * 2 * 128 * 32];  // 32 KB, rows = d
    __shared__ unsigned short Bsh[2 * 2 * 128 * 32];  // 32 KB, rows = n

    const int tid  = threadIdx.x;
    const int wave = tid >> 6;
    const int lane = tid & 63;
    const int wy   = wave >> 1;     // d-direction wave coord (0..1)
    const int wx   = wave & 1;      // n-direction wave coord (0..1)
    const int l31  = lane & 31;
    const int half = lane >> 5;

    // --- XCD-rectangle swizzle (bijection on 64x32 grid) ---
    const int f   = blockIdx.x + ((int)gridDim.x) * blockIdx.y;  // dispatch order
    const int xcd = f & 7;
    const int s   = f >> 3;               // 0..255 within XCD
    const int ntile = (xcd & 3) * 16 + (s & 15);   // 0..63
    const int dtile = (xcd >> 2) * 16 + (s >> 4);  // 0..31
    const int n0 = ntile * 128;
    const int d0 = dtile * 128;

    f32x16 acc[2][2] = {};   // [mi=d-tile][ni=n-tile]

    // staging: one global_load_lds(16B) covers 16 rows x 64 B
    const int srow   = lane >> 2;                               // 0..15
    const int schunk = (((lane & 3) ^ ((srow >> 1) & 3)) * 8);  // swizzled chunk (shorts)

#define STAGE(BUF, KT)                                                              \
    {                                                                               \
        const int kb_ = (KT) * 64;                                                  \
        _Pragma("unroll")                                                           \
        for (int p = 0; p < 2; ++p) {                                               \
            _Pragma("unroll")                                                       \
            for (int jj = 0; jj < 2; ++jj) {                                        \
                const int j = wave * 2 + jj;                                        \
                const unsigned short* ga =                                          \
                    ET + (size_t)(d0 + j * 16 + srow) * K_DIM + kb_ + p * 32 + schunk; \
                __builtin_amdgcn_global_load_lds(                                   \
                    (const __attribute__((address_space(1))) void*)ga,              \
                    (__attribute__((address_space(3))) void*)(Ash + (BUF) * 8192 + p * 4096 + j * 512), \
                    16, 0, 0);                                                      \
                const unsigned short* gb =                                          \
                    FB + (size_t)(n0 + j * 16 + srow) * K_DIM + kb_ + p * 32 + schunk; \
                __builtin_amdgcn_global_load_lds(                                   \
                    (const __attribute__((address_space(1))) void*)gb,              \
                    (__attribute__((address_space(3))) void*)(Bsh + (BUF) * 8192 + p * 4096 + j * 512), \
                    16, 0, 0);                                                      \
            }                                                                       \
        }                                                                           \
    }

    // --- prologue: stage kt=0 into buf 0, wait, barrier ---
    STAGE(0, 0);
    asm volatile("s_waitcnt vmcnt(0)" ::: "memory");
    __builtin_amdgcn_sched_barrier(0);
    __builtin_amdgcn_s_barrier();
    __builtin_amdgcn_sched_barrier(0);

#pragma unroll
    for (int kt = 0; kt < K_DIM / 64; ++kt) {
        const int cur = kt & 1;
        // phase A: issue next tile's staging into the other buffer (no wait).
        // Safe vs WAR: previous iteration's barrier already ended all reads
        // of buf cur^1, and sched_barrier pins this below that barrier.
        if (kt < K_DIM / 64 - 1) STAGE(cur ^ 1, kt + 1);

        // phase B: compute on buf cur (compiler manages lgkmcnt for ds->MFMA)
#pragma unroll
        for (int ks = 0; ks < 4; ++ks) {
            const int p = ks >> 1;
            const int c = (ks & 1) * 2 + half;   // 16B chunk index within row
            bf16x8 af[2], bfr[2];
#pragma unroll
            for (int mi = 0; mi < 2; ++mi) {
                const int R = wy * 64 + mi * 32 + l31;
                const int slot = c ^ ((R >> 1) & 3);
                af[mi] = *reinterpret_cast<const bf16x8*>(
                    Ash + cur * 8192 + p * 4096 + R * 32 + slot * 8);
            }
#pragma unroll
            for (int ni = 0; ni < 2; ++ni) {
                const int R = wx * 64 + ni * 32 + l31;
                const int slot = c ^ ((R >> 1) & 3);
                bfr[ni] = *reinterpret_cast<const bf16x8*>(
                    Bsh + cur * 8192 + p * 4096 + R * 32 + slot * 8);
            }
#pragma unroll
            for (int mi = 0; mi < 2; ++mi)
#pragma unroll
                for (int ni = 0; ni < 2; ++ni)
                    acc[mi][ni] = __builtin_amdgcn_mfma_f32_32x32x16_bf16(
                        af[mi], bfr[ni], acc[mi][ni], 0, 0, 0);
        }

        // phase C: my staging landed; one raw barrier per kt (no lgkm drain
        // needed: all my ds_reads are consumed by MFMAs above).
        __builtin_amdgcn_sched_barrier(0);
        asm volatile("s_waitcnt vmcnt(0)" ::: "memory");
        __builtin_amdgcn_s_barrier();
        __builtin_amdgcn_sched_barrier(0);
    }
#undef STAGE

    // --- epilogue: C layout 32x32: col(n)=lane&31, row(d)=(reg&3)+8*(reg>>2)+4*half
    // W read once device-wide -> non-temporal scalar stream (proven non-lever
    // for scheduling; keep it simple).
    const int nb = n0 + wx * 64;
    float part0 = 0.f, part1 = 0.f;
#pragma unroll
    for (int mi = 0; mi < 2; ++mi) {
        const int dbase = d0 + wy * 64 + mi * 32 + 4 * half;
#pragma unroll
        for (int reg = 0; reg < 16; ++reg) {
            const int dd = dbase + (reg & 3) + 8 * (reg >> 2);
            const float bd = B[dd];
            const float* wr = W + (size_t)dd * N_DIM + nb;
            part0 += (acc[mi][0][reg] + bd) * __builtin_nontemporal_load(wr + l31);
            part1 += (acc[mi][1][reg] + bd) * __builtin_nontemporal_load(wr + 32 + l31);
        }
    }
    part0 += __shfl_xor(part0, 32);
    part1 += __shfl_xor(part1, 32);
    if (lane < 32) {
        atomicAdd(out + nb + l31, part0);
        atomicAdd(out + nb + 32 + l31, part1);
    }
}

extern "C" void kernel_launch(void* const* d_in, const int* in_sizes, int n_in,
                              void* d_out, int out_size, void* d_ws, size_t ws_size,
                              hipStream_t stream) {
    const float* F = (const float*)d_in[0];   // features (N, K)
    const float* W = (const float*)d_in[1];   // w        (D, N)
    const float* E = (const float*)d_in[2];   // E        (K, D)
    const float* B = (const float*)d_in[3];   // b        (D,)
    float* out = (float*)d_out;               // (N,) f32

    unsigned short* ET = (unsigned short*)d_ws;                       // 4 MB
    unsigned short* FB = (unsigned short*)((char*)d_ws + (size_t)D_DIM * K_DIM * 2);  // 8 MB

    transpose_E<<<dim3(D_DIM / 64, K_DIM / 64), 256, 0, stream>>>(E, ET);
    convert_F<<<dim3(N_DIM * K_DIM / (256 * 8)), 256, 0, stream>>>(F, FB, out);
    gemm_fused<<<dim3(N_DIM / 128, D_DIM / 128), 256, 0, stream>>>(FB, W, ET, B, out);
}